// Round 4
// baseline (1487.099 us; speedup 1.0000x reference)
//
#include <hip/hip_runtime.h>
#include <stdint.h>

// ---------------- problem constants ----------------
constexpr int   SEQ  = 8192;
constexpr int   NB   = 64;
constexpr int   ND   = 16;
constexpr float DT    = 0.01f;
constexpr float BETA  = 0.25f;
constexpr float GAMMA = 0.5f;
constexpr float C1 = (0.5f - BETA) * DT * DT;
constexpr float C2 = (1.0f - GAMMA) * DT;
constexpr float C3 = BETA * DT * DT;
constexpr float C4 = GAMMA * DT;
constexpr float E1 = C1 + C3 + DT * C4;   // up' = up + DT*vp + E1*acc
constexpr float E2 = C2 + C4;             // vp' = vp + E2*acc
constexpr float GDT  = GAMMA * DT;
constexpr float BDT2 = BETA * DT * DT;

constexpr int LCH = 16;      // chunk (scan granularity) -- round-0 proven
constexpr int NCH = 512;     // chunks
constexpr size_t BSTRIDE = (size_t)SEQ * ND;
constexpr size_t UOFF = 0;
constexpr size_t VOFF = (size_t)NB * SEQ * ND;
constexpr size_t AOFF = 2 * VOFF;

// ws layout (float offsets) -- EXACT round-0 proven layout, 4.81 MB total.
constexpr int WS_A1T   = 0;       // 768: A1^T,A2^T,A3^T (j*16+d)
constexpr int WS_G4    = 768;     // 1024 each, 32x32 row-major
constexpr int WS_G16   = 1792;
constexpr int WS_G128  = 2816;
constexpr int WS_G1024 = 3840;
constexpr int WS_P1    = 4864;    // 2048: state entering step 1, [r*64+b]
constexpr int WS_ST    = 6912;    // 8   * 2048
constexpr int WS_GT    = 23296;   // 64  * 2048
constexpr int WS_C     = 154368;  // 512 * 2048 chunk totals -> starts

// =====================================================================
// Newmark core: acc = A1*f - A3*up - A2*vp; matrices broadcast from LDS
// (all lanes same address -> conflict-free ds_read_b128; replaces the
// round-0 per-step s_load reload chain that cost ~25k cy/step).
// =====================================================================
__device__ __forceinline__ void nm_acc(const float* __restrict__ sA,
                                       const float f[16], const float up[16],
                                       const float vp[16], float acc[16])
{
    #pragma unroll
    for (int d = 0; d < 16; ++d) acc[d] = 0.f;
    #pragma unroll
    for (int j = 0; j < 16; ++j) {
        const float fj = f[j];
        const float nu = -up[j];
        const float nv = -vp[j];
        #pragma unroll
        for (int q = 0; q < 4; ++q) {
            const float4 m1 = *(const float4*)(sA +       j*16 + 4*q);   // A1^T
            const float4 m2 = *(const float4*)(sA + 256 + j*16 + 4*q);   // A2^T
            const float4 m3 = *(const float4*)(sA + 512 + j*16 + 4*q);   // A3^T
            acc[4*q+0] = fmaf(m1.x, fj, acc[4*q+0]);
            acc[4*q+0] = fmaf(m3.x, nu, acc[4*q+0]);
            acc[4*q+0] = fmaf(m2.x, nv, acc[4*q+0]);
            acc[4*q+1] = fmaf(m1.y, fj, acc[4*q+1]);
            acc[4*q+1] = fmaf(m3.y, nu, acc[4*q+1]);
            acc[4*q+1] = fmaf(m2.y, nv, acc[4*q+1]);
            acc[4*q+2] = fmaf(m1.z, fj, acc[4*q+2]);
            acc[4*q+2] = fmaf(m3.z, nu, acc[4*q+2]);
            acc[4*q+2] = fmaf(m2.z, nv, acc[4*q+2]);
            acc[4*q+3] = fmaf(m1.w, fj, acc[4*q+3]);
            acc[4*q+3] = fmaf(m3.w, nu, acc[4*q+3]);
            acc[4*q+3] = fmaf(m2.w, nv, acc[4*q+3]);
        }
    }
}

__device__ __forceinline__ void nm_update(float up[16], float vp[16], const float acc[16])
{
    #pragma unroll
    for (int d = 0; d < 16; ++d) {
        up[d] = fmaf(DT, vp[d], up[d]);
        up[d] = fmaf(E1, acc[d], up[d]);
        vp[d] = fmaf(E2, acc[d], vp[d]);
    }
}

// ---------------------------------------------------------------------
// Stage one 8-step half of a block's F tile into LDS (XOR-swizzled).
// Per instruction: 2 batches x 512 B fully contiguous (round-0 proven).
// sF[b*128 + (W ^ (b&31))], W = step_in_half*16 + d.
// ---------------------------------------------------------------------
__device__ __forceinline__ void stage_half(const float* __restrict__ F, float* __restrict__ sF,
                                           int l, int w, int s0, int nst, int h)
{
    const int lw  = l & 31;
    const int sin = lw >> 2;
    const bool valid = (8*h + sin) < nst;
    const int W0 = 4*lw;
    #pragma unroll
    for (int p = 0; p < 8; ++p) {
        const int b = p*8 + w*2 + (l >> 5);
        float4 x = make_float4(0.f,0.f,0.f,0.f);
        if (valid) x = *(const float4*)(F + (size_t)b * BSTRIDE + (size_t)(s0 + 8*h) * ND + W0);
        const int cb = b & 31;
        sF[b*128 + ((W0+0) ^ cb)] = x.x;
        sF[b*128 + ((W0+1) ^ cb)] = x.y;
        sF[b*128 + ((W0+2) ^ cb)] = x.z;
        sF[b*128 + ((W0+3) ^ cb)] = x.w;
    }
}

// ---------------------------------------------------------------------
// Drain one array's 4-step group from LDS to global (256 B runs/instr).
// so layout: so[b*64 + (e ^ (b&31))], e = i*16 + d (i = step in group).
// ---------------------------------------------------------------------
__device__ __forceinline__ void drain_arr(const float* __restrict__ so_w,
                                          float* __restrict__ gbase,
                                          int l, int nstc)
{
    const int m = l & 15, dlt = l >> 4;
    const bool ok = (m >> 2) < nstc;
    #pragma unroll
    for (int g = 0; g < 16; ++g) {
        const int b = g*4 + dlt;
        const int cb = b & 31;
        float4 x;
        x.x = so_w[b*64 + ((4*m+0) ^ cb)];
        x.y = so_w[b*64 + ((4*m+1) ^ cb)];
        x.z = so_w[b*64 + ((4*m+2) ^ cb)];
        x.w = so_w[b*64 + ((4*m+3) ^ cb)];
        if (ok) *(float4*)(gbase + (size_t)b * BSTRIDE + 4*m) = x;
    }
}

// =====================================================================
// K0: invert K_eff & M, A2/A3, G powers {4,16,128,1024}, p1 seed,
// step-0 outputs. One block, 512 threads. (round-0 proven)
// =====================================================================
__global__ __launch_bounds__(512) void setup_k(const float* __restrict__ F,
                                               const float* __restrict__ Mg,
                                               const float* __restrict__ Cg,
                                               const float* __restrict__ Kg,
                                               float* __restrict__ ws,
                                               float* __restrict__ out)
{
    __shared__ float sM[256], sC[256], sK[256];
    __shared__ float aug[16][33];
    __shared__ float A1s[256], A2s[256], A3s[256], Mis[256];
    __shared__ float bA[1024], bB[1024];
    const int tid = threadIdx.x;
    if (tid < 256) { sM[tid] = Mg[tid]; sC[tid] = Cg[tid]; sK[tid] = Kg[tid]; }
    __syncthreads();

    const int r = tid >> 5, c = tid & 31;
    {
        float v;
        if (c < 16) v = sM[r*16+c] + GDT * sC[r*16+c] + BDT2 * sK[r*16+c];
        else        v = (c - 16 == r) ? 1.f : 0.f;
        aug[r][c] = v;
    }
    __syncthreads();
    for (int kk = 0; kk < 16; ++kk) {
        float pv   = aug[kk][kk];
        float fr   = aug[r][kk];
        float akc  = aug[kk][c];
        float curv = aug[r][c];
        __syncthreads();
        float inv = 1.0f / pv;
        aug[r][c] = (r == kk) ? curv * inv : fmaf(-fr * inv, akc, curv);
        __syncthreads();
    }
    if (tid < 256) A1s[tid] = aug[tid >> 4][(tid & 15) + 16];
    __syncthreads();

    aug[r][c] = (c < 16) ? sM[r*16+c] : ((c - 16 == r) ? 1.f : 0.f);
    __syncthreads();
    for (int kk = 0; kk < 16; ++kk) {
        float pv   = aug[kk][kk];
        float fr   = aug[r][kk];
        float akc  = aug[kk][c];
        float curv = aug[r][c];
        __syncthreads();
        float inv = 1.0f / pv;
        aug[r][c] = (r == kk) ? curv * inv : fmaf(-fr * inv, akc, curv);
        __syncthreads();
    }
    if (tid < 256) Mis[tid] = aug[tid >> 4][(tid & 15) + 16];
    __syncthreads();

    if (tid < 256) {
        const int rr = tid >> 4, cc = tid & 15;
        float a2 = 0.f, a3 = 0.f;
        #pragma unroll
        for (int j = 0; j < 16; ++j) {
            const float a = A1s[rr*16+j];
            a2 = fmaf(a, sC[j*16+cc], a2);
            a3 = fmaf(a, sK[j*16+cc], a3);
        }
        A2s[tid] = a2; A3s[tid] = a3;
    }
    __syncthreads();

    if (tid < 256) {
        const int j = tid >> 4, d = tid & 15;
        ws[WS_A1T +       tid] = A1s[d*16+j];
        ws[WS_A1T + 256 + tid] = A2s[d*16+j];
        ws[WS_A1T + 512 + tid] = A3s[d*16+j];
    }
    for (int idx = tid; idx < 1024; idx += 512) {
        const int i = idx >> 5, j = idx & 31;
        float v;
        if (i < 16) {
            if (j < 16) v = ((i == j) ? 1.f : 0.f) - E1 * A3s[i*16+j];
            else        v = ((i == j - 16) ? DT : 0.f) - E1 * A2s[i*16+(j-16)];
        } else {
            const int i2 = i - 16;
            if (j < 16) v = -E2 * A3s[i2*16+j];
            else        v = ((i2 == j - 16) ? 1.f : 0.f) - E2 * A2s[i2*16+(j-16)];
        }
        bA[idx] = v;
    }
    __syncthreads();
    // after iter s: bA = G^(2^(s+1)); store G4(s=1), G16(s=3), G128(s=6), G1024(end)
    for (int s = 0; s < 10; ++s) {
        for (int idx = tid; idx < 1024; idx += 512) {
            const int i = idx >> 5, j = idx & 31;
            float acc = 0.f;
            #pragma unroll
            for (int q = 0; q < 32; ++q) acc = fmaf(bA[i*32+q], bA[q*32+j], acc);
            bB[idx] = acc;
        }
        __syncthreads();
        for (int idx = tid; idx < 1024; idx += 512) bA[idx] = bB[idx];
        __syncthreads();
        if (s == 1) for (int idx = tid; idx < 1024; idx += 512) ws[WS_G4   + idx] = bA[idx];
        if (s == 3) for (int idx = tid; idx < 1024; idx += 512) ws[WS_G16  + idx] = bA[idx];
        if (s == 6) for (int idx = tid; idx < 1024; idx += 512) ws[WS_G128 + idx] = bA[idx];
    }
    for (int idx = tid; idx < 1024; idx += 512) ws[WS_G1024 + idx] = bA[idx];

    // step-0 outputs + p1 seed (state entering step 1): up=C1*a0, vp=C2*a0
    for (int t = tid; t < 1024; t += 512) {
        const int b = t >> 4, d = t & 15;
        float s0 = 0.f;
        #pragma unroll
        for (int j = 0; j < 16; ++j) s0 = fmaf(Mis[d*16+j], F[(size_t)b * BSTRIDE + j], s0);
        out[UOFF + (size_t)b * BSTRIDE + d] = 0.f;
        out[VOFF + (size_t)b * BSTRIDE + d] = 0.f;
        out[AOFF + (size_t)b * BSTRIDE + d] = s0;
        ws[WS_P1 + d*64 + b]        = C1 * s0;
        ws[WS_P1 + (16 + d)*64 + b] = C2 * s0;
    }
}

// =====================================================================
// K1: 16-step chunk totals. 512 blocks x 256 thr. Each wave computes a
// 4-step probe total from zero (LDS-matrix steps), then a G4 fold in
// LDS composes them into the chunk total (round-0 proven dataflow).
// =====================================================================
__global__ __launch_bounds__(256, 2) void phase1_k(const float* __restrict__ F,
                                                   const float* __restrict__ ws)
{
    alignas(16) __shared__ float sA[768];
    alignas(16) __shared__ float sG4[1024];
    __shared__ float sF[64*128];    // 32 KB
    __shared__ float st[4][2048];   // 32 KB sub-totals / fold buffers
    const int tid = threadIdx.x;
    for (int i = tid; i < 768;  i += 256) sA[i]  = ws[WS_A1T + i];
    for (int i = tid; i < 1024; i += 256) sG4[i] = ws[WS_G4  + i];
    const int w = tid >> 6, l = tid & 63;
    const int k = blockIdx.x;
    const int s0 = LCH * k + 1;
    const int nst = min(LCH, SEQ - s0);
    const int c = l & 31;

    float up[16], vp[16], acc[16];
    #pragma unroll
    for (int d = 0; d < 16; ++d) { up[d] = 0.f; vp[d] = 0.f; }

    stage_half(F, sF, l, w, s0, nst, 0);
    __syncthreads();
    if (w < 2) {
        #pragma unroll
        for (int i = 0; i < 4; ++i) {
            const int t = 4*w + i;                 // 0..7, always < nst (>=15)
            float f[16];
            #pragma unroll
            for (int d = 0; d < 16; ++d) f[d] = sF[l*128 + ((((t&7)*16) + d) ^ c)];
            nm_acc(sA, f, up, vp, acc);
            nm_update(up, vp, acc);
        }
        #pragma unroll
        for (int d = 0; d < 16; ++d) { st[w][d*64 + l] = up[d]; st[w][(16+d)*64 + l] = vp[d]; }
    }
    __syncthreads();
    stage_half(F, sF, l, w, s0, nst, 1);
    __syncthreads();
    if (w >= 2) {
        #pragma unroll
        for (int i = 0; i < 4; ++i) {
            const int t = 4*w + i;                 // 8..15
            if (t < nst) {
                float f[16];
                #pragma unroll
                for (int d = 0; d < 16; ++d) f[d] = sF[l*128 + ((((t&7)*16) + d) ^ c)];
                nm_acc(sA, f, up, vp, acc);
                nm_update(up, vp, acc);
            }
        }
        #pragma unroll
        for (int d = 0; d < 16; ++d) { st[w][d*64 + l] = up[d]; st[w][(16+d)*64 + l] = vp[d]; }
    }
    __syncthreads();

    // fold: cum = st[0]; st[r] <- G4*cum + st[r]  (cum = st[r-1])
    const int wr = __builtin_amdgcn_readfirstlane(tid >> 6);
    float n[8];
    for (int r = 1; r < 4; ++r) {
        #pragma unroll
        for (int q = 0; q < 8; ++q) n[q] = st[r][(wr+4*q)*64 + l];
        #pragma unroll
        for (int j = 0; j < 32; ++j) {
            const float pj = st[r-1][j*64 + l];
            #pragma unroll
            for (int q = 0; q < 8; ++q) n[q] = fmaf(sG4[(wr+4*q)*32 + j], pj, n[q]);
        }
        if (r < 3) {
            #pragma unroll
            for (int q = 0; q < 8; ++q) st[r][(wr+4*q)*64 + l] = n[q];
            __syncthreads();
        }
    }
    float* __restrict__ cb = (float*)ws + WS_C + (size_t)k * 2048;
    #pragma unroll
    for (int q = 0; q < 8; ++q) cb[(wr+4*q)*64 + l] = n[q];
}

// =====================================================================
// K2: affine scan p' = Gm*p + c_k. Layout [r*64+b] throughout.
// G staged in LDS (broadcast float4 reads); p double-buffered in LDS;
// c_k read BEFORE the down-sweep start-overwrite.
// =====================================================================
__global__ __launch_bounds__(256, 4) void scan_k(const float* __restrict__ Gm,
                                                 float* __restrict__ cbase,
                                                 const float* __restrict__ seed,
                                                 float* __restrict__ totals,
                                                 int nIter)
{
    alignas(16) __shared__ float sG[1024];
    __shared__ float pb[2][2048];
    const int tid = threadIdx.x;
    const int b = tid & 63;
    const int w = tid >> 6;
    const int g = blockIdx.x;
    for (int i = tid; i < 1024; i += 256) sG[i] = Gm[i];

    float pr[8];
    #pragma unroll
    for (int q = 0; q < 8; ++q) {
        const int r = w + 4*q;
        pr[q] = (seed != nullptr) ? seed[(size_t)g * 2048 + r*64 + b] : 0.f;
        pb[0][r*64 + b] = pr[q];
    }
    __syncthreads();
    int cur = 0;
    float* cslot = cbase + (size_t)g * nIter * 2048;
    for (int k = 0; k < nIter; ++k) {
        float n[8];
        #pragma unroll
        for (int q = 0; q < 8; ++q) n[q] = cslot[(w + 4*q)*64 + b];       // c_k (old)
        if (totals == nullptr) {
            #pragma unroll
            for (int q = 0; q < 8; ++q) cslot[(w + 4*q)*64 + b] = pr[q];  // write start
        }
        #pragma unroll
        for (int j4 = 0; j4 < 8; ++j4) {
            const float p0 = pb[cur][(4*j4+0)*64 + b];
            const float p1 = pb[cur][(4*j4+1)*64 + b];
            const float p2 = pb[cur][(4*j4+2)*64 + b];
            const float p3 = pb[cur][(4*j4+3)*64 + b];
            #pragma unroll
            for (int q = 0; q < 8; ++q) {
                const float4 gq = *(const float4*)&sG[(w + 4*q)*32 + 4*j4];
                n[q] = fmaf(gq.x, p0, n[q]);
                n[q] = fmaf(gq.y, p1, n[q]);
                n[q] = fmaf(gq.z, p2, n[q]);
                n[q] = fmaf(gq.w, p3, n[q]);
            }
        }
        #pragma unroll
        for (int q = 0; q < 8; ++q) { pr[q] = n[q]; pb[cur ^ 1][(w + 4*q)*64 + b] = n[q]; }
        cur ^= 1;
        cslot += 2048;
        __syncthreads();
    }
    if (totals != nullptr) {
        #pragma unroll
        for (int q = 0; q < 8; ++q) totals[(size_t)g * 2048 + (w + 4*q)*64 + b] = pr[q];
    }
}

// =====================================================================
// K3: outputs. 512 blocks x 256 thr. Warm-up ladder 0/4/8/12 across the
// 4 waves (round-0 proven dataflow); steps via LDS-matrix nm_acc
// (~2.5k cy/step vs round-0's ~25k s_load-bound). Outputs staged in so
// and drained as 256 B runs; v,a kept in registers during the u drain.
// =====================================================================
__global__ __launch_bounds__(256, 2) void phase3_k(const float* __restrict__ F,
                                                   const float* __restrict__ ws,
                                                   float* __restrict__ out)
{
    alignas(16) __shared__ float sA[768];
    __shared__ float sF[64*128];     // 32 KB
    __shared__ float so[2][4096];    // 32 KB: 2 concurrent waves' out staging
    const int tid = threadIdx.x;
    for (int i = tid; i < 768; i += 256) sA[i] = ws[WS_A1T + i];
    const int w = tid >> 6, l = tid & 63;
    const int k = blockIdx.x;
    const int s0 = LCH * k + 1;
    const int nst = min(LCH, SEQ - s0);
    const int s0c = s0 + 4*w;
    const int nstc = min(4, SEQ - s0c);
    const int c = l & 31;

    // chunk start (down-swept), coalesced 256 B/instr reads
    const float* stt = (const float*)ws + WS_C + (size_t)k * 2048;
    float up[16], vp[16], acc[16];
    #pragma unroll
    for (int d = 0; d < 16; ++d) { up[d] = stt[d*64 + l]; vp[d] = stt[(16+d)*64 + l]; }

    float vo[4][16], ao[4][16];
    float* so_w = &so[w & 1][0];
    float* gu = out + UOFF + (size_t)s0c * ND;
    float* gv = out + VOFF + (size_t)s0c * ND;
    float* ga = out + AOFF + (size_t)s0c * ND;

    stage_half(F, sF, l, w, s0, nst, 0);
    __syncthreads();
    if (w < 2) {
        // warm-up (wave1: steps 0-3), then outputs 4w..4w+3
        for (int i = 0; i < 4*w; ++i) {
            float f[16];
            #pragma unroll
            for (int d = 0; d < 16; ++d) f[d] = sF[l*128 + (((i&7)*16 + d) ^ c)];
            nm_acc(sA, f, up, vp, acc);
            nm_update(up, vp, acc);
        }
        #pragma unroll
        for (int i = 0; i < 4; ++i) {
            const int t = 4*w + i;                 // <= 7
            float f[16];
            #pragma unroll
            for (int d = 0; d < 16; ++d) f[d] = sF[l*128 + (((t&7)*16 + d) ^ c)];
            nm_acc(sA, f, up, vp, acc);
            #pragma unroll
            for (int d = 0; d < 16; ++d) {
                so_w[l*64 + ((i*16+d) ^ c)] = fmaf(C3, acc[d], up[d]);
                vo[i][d] = fmaf(C4, acc[d], vp[d]);
                ao[i][d] = acc[d];
            }
            nm_update(up, vp, acc);
        }
        drain_arr(so_w, gu, l, nstc);
        #pragma unroll
        for (int i = 0; i < 4; ++i)
            #pragma unroll
            for (int d = 0; d < 16; ++d) so_w[l*64 + ((i*16+d) ^ c)] = vo[i][d];
        drain_arr(so_w, gv, l, nstc);
        #pragma unroll
        for (int i = 0; i < 4; ++i)
            #pragma unroll
            for (int d = 0; d < 16; ++d) so_w[l*64 + ((i*16+d) ^ c)] = ao[i][d];
        drain_arr(so_w, ga, l, nstc);
    } else {
        // waves 2,3: warm through steps 0-7
        for (int i = 0; i < 8; ++i) {
            float f[16];
            #pragma unroll
            for (int d = 0; d < 16; ++d) f[d] = sF[l*128 + (((i&7)*16 + d) ^ c)];
            nm_acc(sA, f, up, vp, acc);
            nm_update(up, vp, acc);
        }
    }
    __syncthreads();
    stage_half(F, sF, l, w, s0, nst, 1);
    __syncthreads();

    if (w >= 2) {
        if (w == 3) {
            for (int i = 8; i < 12; ++i) {
                float f[16];
                #pragma unroll
                for (int d = 0; d < 16; ++d) f[d] = sF[l*128 + (((i&7)*16 + d) ^ c)];
                nm_acc(sA, f, up, vp, acc);
                nm_update(up, vp, acc);
            }
        }
        #pragma unroll
        for (int i = 0; i < 4; ++i) {
            const int t = 4*w + i;                 // 8..15
            if (t < nst) {
                float f[16];
                #pragma unroll
                for (int d = 0; d < 16; ++d) f[d] = sF[l*128 + (((t&7)*16 + d) ^ c)];
                nm_acc(sA, f, up, vp, acc);
                #pragma unroll
                for (int d = 0; d < 16; ++d) {
                    so_w[l*64 + ((i*16+d) ^ c)] = fmaf(C3, acc[d], up[d]);
                    vo[i][d] = fmaf(C4, acc[d], vp[d]);
                    ao[i][d] = acc[d];
                }
                nm_update(up, vp, acc);
            }
        }
        drain_arr(so_w, gu, l, nstc);
        #pragma unroll
        for (int i = 0; i < 4; ++i)
            #pragma unroll
            for (int d = 0; d < 16; ++d) so_w[l*64 + ((i*16+d) ^ c)] = vo[i][d];
        drain_arr(so_w, gv, l, nstc);
        #pragma unroll
        for (int i = 0; i < 4; ++i)
            #pragma unroll
            for (int d = 0; d < 16; ++d) so_w[l*64 + ((i*16+d) ^ c)] = ao[i][d];
        drain_arr(so_w, ga, l, nstc);
    }
}

// =====================================================================
// Hierarchy (round-0 proven): 512 16-step chunks, radix-8:
//   up:  G16 (64 grps) -> G128 (8) -> top G1024 (1 grp, 8 it, seed P1,
//        starts into ST)
//   down: G128 -> G16 (starts into C)
// =====================================================================
extern "C" void kernel_launch(void* const* d_in, const int* in_sizes, int n_in,
                              void* d_out, int out_size, void* d_ws, size_t ws_size,
                              hipStream_t stream)
{
    const float* F = (const float*)d_in[0];
    const float* M = (const float*)d_in[1];
    const float* C = (const float*)d_in[2];
    const float* K = (const float*)d_in[3];
    float* out = (float*)d_out;
    float* ws  = (float*)d_ws;

    setup_k <<<1,   512, 0, stream>>>(F, M, C, K, ws, out);
    phase1_k<<<NCH, 256, 0, stream>>>(F, ws);
    scan_k  <<<64,  256, 0, stream>>>(ws + WS_G16,   ws + WS_C,  nullptr,     ws + WS_GT, 8);
    scan_k  <<<8,   256, 0, stream>>>(ws + WS_G128,  ws + WS_GT, nullptr,     ws + WS_ST, 8);
    scan_k  <<<1,   256, 0, stream>>>(ws + WS_G1024, ws + WS_ST, ws + WS_P1,  nullptr,    8);
    scan_k  <<<8,   256, 0, stream>>>(ws + WS_G128,  ws + WS_GT, ws + WS_ST,  nullptr,    8);
    scan_k  <<<64,  256, 0, stream>>>(ws + WS_G16,   ws + WS_C,  ws + WS_GT,  nullptr,    8);
    phase3_k<<<NCH, 256, 0, stream>>>(F, ws, out);
}

// Round 5
// 395.474 us; speedup vs baseline: 3.7603x; 3.7603x over previous
//
#include <hip/hip_runtime.h>
#include <stdint.h>

// ---------------- problem constants ----------------
constexpr int   SEQ  = 8192;
constexpr int   NB   = 64;
constexpr int   ND   = 16;
constexpr float DT    = 0.01f;
constexpr float BETA  = 0.25f;
constexpr float GAMMA = 0.5f;
constexpr float C1 = (0.5f - BETA) * DT * DT;
constexpr float C2 = (1.0f - GAMMA) * DT;
constexpr float C3 = BETA * DT * DT;
constexpr float C4 = GAMMA * DT;
constexpr float E1 = C1 + C3 + DT * C4;   // up' = up + DT*vp + E1*acc
constexpr float E2 = C2 + C4;             // vp' = vp + E2*acc
constexpr float GDT  = GAMMA * DT;
constexpr float BDT2 = BETA * DT * DT;

constexpr size_t BSTRIDE = (size_t)SEQ * ND;
constexpr size_t UOFF = 0;
constexpr size_t VOFF = (size_t)NB * SEQ * ND;
constexpr size_t AOFF = 2 * VOFF;

// ws layout (float offsets), ~2.4 MB total (< proven 4.81 MB)
constexpr int WS_A1T   = 0;                    // 768: A1^T,A2^T,A3^T (j*16+d)
constexpr int WS_G4    = 768;                  // 1024 each, 32x32 row-major
constexpr int WS_G32   = 1792;
constexpr int WS_G256  = 2816;
constexpr int WS_G2048 = 3840;
constexpr int WS_P1    = 4864;                 // 2048: state entering step 1, [r*64+b]
constexpr int WS_T1    = 8192;                 // 256 * 2048
constexpr int WS_T2    = WS_T1 + 256 * 2048;   // 32  * 2048
constexpr int WS_T3    = WS_T2 + 32 * 2048;    // 4   * 2048

// 2048 4-step chunk totals (up-sweep) -> chunk entry states (down-sweep).
// Layout [chunk][r*64 + b]: every access is a 256 B-contiguous run/instr.
__device__ float g_cbuf[(size_t)2048 * 2048];

// ---------------------------------------------------------------------
// Stage one 8-step half of a block's F tile into LDS (XOR-swizzled).
// Per instruction: 2 batches x 512 B fully contiguous (R0-proven).
// sF[b*128 + (W ^ (b&31))], W = step_in_half*16 + d.
// ---------------------------------------------------------------------
__device__ __forceinline__ void stage_half(const float* __restrict__ F, float* __restrict__ sF,
                                           int l, int w, int s0, int nst, int h)
{
    const int lw  = l & 31;
    const int sin = lw >> 2;
    const bool valid = (8*h + sin) < nst;
    const int W0 = 4*lw;
    #pragma unroll
    for (int p = 0; p < 8; ++p) {
        const int b = p*8 + w*2 + (l >> 5);
        float4 x = make_float4(0.f,0.f,0.f,0.f);
        if (valid) x = *(const float4*)(F + (size_t)b * BSTRIDE + (size_t)(s0 + 8*h) * ND + W0);
        const int cb = b & 31;
        sF[b*128 + ((W0+0) ^ cb)] = x.x;
        sF[b*128 + ((W0+1) ^ cb)] = x.y;
        sF[b*128 + ((W0+2) ^ cb)] = x.z;
        sF[b*128 + ((W0+3) ^ cb)] = x.w;
    }
}

// ---------------------------------------------------------------------
// One Newmark step; F from LDS (lane = batch), matrices via s_load
// (anti-LICM reload each step: operands stream through SGPRs, keeping
// VGPR pressure low -- the R0-proven form; LDS-matrix variant spilled).
// ---------------------------------------------------------------------
__device__ __forceinline__ void newmark_step_lds(uintptr_t wsa, const float* __restrict__ sF,
                                                 int l, int sin,
                                                 float up[16], float vp[16], float acc[16])
{
    uintptr_t wsl = wsa;
    asm volatile("" : "+s"(wsl));
    const float* __restrict__ A1t = (const float*)wsl;
    const float* __restrict__ A2t = A1t + 256;
    const float* __restrict__ A3t = A1t + 512;
    const int c = l & 31;
    const int base = l*128;
    float f[16];
    #pragma unroll
    for (int d = 0; d < 16; ++d) f[d] = sF[base + ((sin*16 + d) ^ c)];
    #pragma unroll
    for (int d = 0; d < 16; ++d) acc[d] = 0.f;
    #pragma unroll
    for (int j = 0; j < 16; ++j) {
        const float fj = f[j], nu = -up[j], nv = -vp[j];
        #pragma unroll
        for (int d = 0; d < 16; ++d) {
            acc[d] = fmaf(A1t[j*16+d], fj, acc[d]);
            acc[d] = fmaf(A3t[j*16+d], nu, acc[d]);
            acc[d] = fmaf(A2t[j*16+d], nv, acc[d]);
        }
    }
    #pragma unroll
    for (int d = 0; d < 16; ++d) {
        up[d] = fmaf(DT, vp[d], up[d]);
        up[d] = fmaf(E1, acc[d], up[d]);
        vp[d] = fmaf(E2, acc[d], vp[d]);
    }
}

// ---------------------------------------------------------------------
// Drain one array's 4-step group from LDS to global (256 B runs/instr).
// so layout: so[b*64 + (e ^ (b&31))], e = i*16 + d (i = step in group).
// ---------------------------------------------------------------------
__device__ __forceinline__ void drain_arr(const float* __restrict__ so_w,
                                          float* __restrict__ gbase,
                                          int l, int nstc)
{
    const int m = l & 15, dlt = l >> 4;
    const bool ok = (m >> 2) < nstc;
    #pragma unroll
    for (int g = 0; g < 16; ++g) {
        const int b = g*4 + dlt;
        const int cb = b & 31;
        float4 x;
        x.x = so_w[b*64 + ((4*m+0) ^ cb)];
        x.y = so_w[b*64 + ((4*m+1) ^ cb)];
        x.z = so_w[b*64 + ((4*m+2) ^ cb)];
        x.w = so_w[b*64 + ((4*m+3) ^ cb)];
        if (ok) *(float4*)(gbase + (size_t)b * BSTRIDE + 4*m) = x;
    }
}

// =====================================================================
// K0: invert K_eff & M, A2/A3 (transposed to ws), G powers
// {4,32,256,2048}, p1 seed, step-0 outputs. One block, 512 threads.
// =====================================================================
__global__ __launch_bounds__(512) void setup_k(const float* __restrict__ F,
                                               const float* __restrict__ Mg,
                                               const float* __restrict__ Cg,
                                               const float* __restrict__ Kg,
                                               float* __restrict__ ws,
                                               float* __restrict__ out)
{
    __shared__ float sM[256], sC[256], sK[256];
    __shared__ float aug[16][33];
    __shared__ float A1s[256], A2s[256], A3s[256], Mis[256];
    __shared__ float bA[1024], bB[1024];
    const int tid = threadIdx.x;
    if (tid < 256) { sM[tid] = Mg[tid]; sC[tid] = Cg[tid]; sK[tid] = Kg[tid]; }
    __syncthreads();

    const int r = tid >> 5, c = tid & 31;
    {
        float v;
        if (c < 16) v = sM[r*16+c] + GDT * sC[r*16+c] + BDT2 * sK[r*16+c];
        else        v = (c - 16 == r) ? 1.f : 0.f;
        aug[r][c] = v;
    }
    __syncthreads();
    for (int kk = 0; kk < 16; ++kk) {
        float pv   = aug[kk][kk];
        float fr   = aug[r][kk];
        float akc  = aug[kk][c];
        float curv = aug[r][c];
        __syncthreads();
        float inv = 1.0f / pv;
        aug[r][c] = (r == kk) ? curv * inv : fmaf(-fr * inv, akc, curv);
        __syncthreads();
    }
    if (tid < 256) A1s[tid] = aug[tid >> 4][(tid & 15) + 16];
    __syncthreads();

    aug[r][c] = (c < 16) ? sM[r*16+c] : ((c - 16 == r) ? 1.f : 0.f);
    __syncthreads();
    for (int kk = 0; kk < 16; ++kk) {
        float pv   = aug[kk][kk];
        float fr   = aug[r][kk];
        float akc  = aug[kk][c];
        float curv = aug[r][c];
        __syncthreads();
        float inv = 1.0f / pv;
        aug[r][c] = (r == kk) ? curv * inv : fmaf(-fr * inv, akc, curv);
        __syncthreads();
    }
    if (tid < 256) Mis[tid] = aug[tid >> 4][(tid & 15) + 16];
    __syncthreads();

    if (tid < 256) {
        const int rr = tid >> 4, cc = tid & 15;
        float a2 = 0.f, a3 = 0.f;
        #pragma unroll
        for (int j = 0; j < 16; ++j) {
            const float a = A1s[rr*16+j];
            a2 = fmaf(a, sC[j*16+cc], a2);
            a3 = fmaf(a, sK[j*16+cc], a3);
        }
        A2s[tid] = a2; A3s[tid] = a3;
    }
    __syncthreads();

    if (tid < 256) {
        const int j = tid >> 4, d = tid & 15;
        ws[WS_A1T +       tid] = A1s[d*16+j];
        ws[WS_A1T + 256 + tid] = A2s[d*16+j];
        ws[WS_A1T + 512 + tid] = A3s[d*16+j];
    }
    for (int idx = tid; idx < 1024; idx += 512) {
        const int i = idx >> 5, j = idx & 31;
        float v;
        if (i < 16) {
            if (j < 16) v = ((i == j) ? 1.f : 0.f) - E1 * A3s[i*16+j];
            else        v = ((i == j - 16) ? DT : 0.f) - E1 * A2s[i*16+(j-16)];
        } else {
            const int i2 = i - 16;
            if (j < 16) v = -E2 * A3s[i2*16+j];
            else        v = ((i2 == j - 16) ? 1.f : 0.f) - E2 * A2s[i2*16+(j-16)];
        }
        bA[idx] = v;
    }
    __syncthreads();
    // after iter s: bA = G^(2^(s+1)); store G4(s=1), G32(s=4), G256(s=7), G2048(end)
    for (int s = 0; s < 11; ++s) {
        for (int idx = tid; idx < 1024; idx += 512) {
            const int i = idx >> 5, j = idx & 31;
            float acc = 0.f;
            #pragma unroll
            for (int q = 0; q < 32; ++q) acc = fmaf(bA[i*32+q], bA[q*32+j], acc);
            bB[idx] = acc;
        }
        __syncthreads();
        for (int idx = tid; idx < 1024; idx += 512) bA[idx] = bB[idx];
        __syncthreads();
        if (s == 1) for (int idx = tid; idx < 1024; idx += 512) ws[WS_G4   + idx] = bA[idx];
        if (s == 4) for (int idx = tid; idx < 1024; idx += 512) ws[WS_G32  + idx] = bA[idx];
        if (s == 7) for (int idx = tid; idx < 1024; idx += 512) ws[WS_G256 + idx] = bA[idx];
    }
    for (int idx = tid; idx < 1024; idx += 512) ws[WS_G2048 + idx] = bA[idx];

    // step-0 outputs + p1 seed (state entering step 1): up=C1*a0, vp=C2*a0
    for (int t = tid; t < 1024; t += 512) {
        const int b = t >> 4, d = t & 15;
        float s0 = 0.f;
        #pragma unroll
        for (int j = 0; j < 16; ++j) s0 = fmaf(Mis[d*16+j], F[(size_t)b * BSTRIDE + j], s0);
        out[UOFF + (size_t)b * BSTRIDE + d] = 0.f;
        out[VOFF + (size_t)b * BSTRIDE + d] = 0.f;
        out[AOFF + (size_t)b * BSTRIDE + d] = s0;
        ws[WS_P1 + d*64 + b]        = C1 * s0;
        ws[WS_P1 + (16 + d)*64 + b] = C2 * s0;
    }
}

// =====================================================================
// K1: 4-step chunk totals. 512 blocks x 256 thr; both 8-step halves of
// the block's 16-step F tile staged up-front (double buffer, ONE
// barrier); wave w runs exactly 4 steps from zero = chunk 4*blk+w's
// total (no fold). Totals stored [r*64+b], 256 B/instr.
// =====================================================================
__global__ __launch_bounds__(256, 2) void phase1_k(const float* __restrict__ F,
                                                   const float* ws_in)
{
    __shared__ float sF0[64*128];   // 32 KB: steps 0-7
    __shared__ float sF1[64*128];   // 32 KB: steps 8-15
    const int tid = threadIdx.x;
    const int w = tid >> 6, l = tid & 63;
    const int blk = blockIdx.x;
    const int s0 = 16*blk + 1;
    const int nst = min(16, SEQ - s0);
    const uintptr_t wsa = (uintptr_t)ws_in;

    float up[16], vp[16], acc[16];
    #pragma unroll
    for (int d = 0; d < 16; ++d) { up[d] = 0.f; vp[d] = 0.f; }

    stage_half(F, sF0, l, w, s0, nst, 0);
    stage_half(F, sF1, l, w, s0, nst, 1);
    __syncthreads();

    const float* sFw = (w < 2) ? sF0 : sF1;
    #pragma unroll
    for (int i = 0; i < 4; ++i) {
        const int t = 4*w + i;
        if (t < nst) newmark_step_lds(wsa, sFw, l, t & 7, up, vp, acc);
    }

    float* cb = g_cbuf + (size_t)(4*blk + w) * 2048;
    #pragma unroll
    for (int d = 0; d < 16; ++d) { cb[d*64 + l] = up[d]; cb[(16+d)*64 + l] = vp[d]; }
}

// =====================================================================
// K2: affine scan p' = Gm*p + c_k. Layout [r*64+b] throughout.
// G staged in LDS (broadcast float4 reads); p double-buffered in LDS;
// c_k read BEFORE the down-sweep start-overwrite.
// =====================================================================
__global__ __launch_bounds__(256, 4) void scan_k(const float* __restrict__ Gm,
                                                 float* cbase_ws, int use_gcbuf,
                                                 const float* __restrict__ seed,
                                                 float* __restrict__ totals,
                                                 int nIter)
{
    alignas(16) __shared__ float sG[1024];
    __shared__ float pb[2][2048];
    float* cbase = use_gcbuf ? g_cbuf : cbase_ws;
    const int tid = threadIdx.x;
    const int b = tid & 63;
    const int w = tid >> 6;
    const int g = blockIdx.x;
    for (int i = tid; i < 1024; i += 256) sG[i] = Gm[i];

    float pr[8];
    #pragma unroll
    for (int q = 0; q < 8; ++q) {
        const int r = w + 4*q;
        pr[q] = (seed != nullptr) ? seed[(size_t)g * 2048 + r*64 + b] : 0.f;
        pb[0][r*64 + b] = pr[q];
    }
    __syncthreads();
    int cur = 0;
    float* cslot = cbase + (size_t)g * nIter * 2048;
    for (int k = 0; k < nIter; ++k) {
        float n[8];
        #pragma unroll
        for (int q = 0; q < 8; ++q) n[q] = cslot[(w + 4*q)*64 + b];       // c_k (old)
        if (totals == nullptr) {
            #pragma unroll
            for (int q = 0; q < 8; ++q) cslot[(w + 4*q)*64 + b] = pr[q];  // write start
        }
        #pragma unroll
        for (int j4 = 0; j4 < 8; ++j4) {
            const float p0 = pb[cur][(4*j4+0)*64 + b];
            const float p1 = pb[cur][(4*j4+1)*64 + b];
            const float p2 = pb[cur][(4*j4+2)*64 + b];
            const float p3 = pb[cur][(4*j4+3)*64 + b];
            #pragma unroll
            for (int q = 0; q < 8; ++q) {
                const float4 gq = *(const float4*)&sG[(w + 4*q)*32 + 4*j4];
                n[q] = fmaf(gq.x, p0, n[q]);
                n[q] = fmaf(gq.y, p1, n[q]);
                n[q] = fmaf(gq.z, p2, n[q]);
                n[q] = fmaf(gq.w, p3, n[q]);
            }
        }
        #pragma unroll
        for (int q = 0; q < 8; ++q) { pr[q] = n[q]; pb[cur ^ 1][(w + 4*q)*64 + b] = n[q]; }
        cur ^= 1;
        cslot += 2048;
        __syncthreads();
    }
    if (totals != nullptr) {
        #pragma unroll
        for (int q = 0; q < 8; ++q) totals[(size_t)g * 2048 + (w + 4*q)*64 + b] = pr[q];
    }
}

// =====================================================================
// K3: outputs. 512 blocks x 256 thr; wave w starts from its own
// down-swept chunk state -- exactly 4 steps/wave, ZERO warm-up (R0's
// ladder made the critical wave do 16). All inner-loop code is R0's
// proven-clean form (s_load matrices, staged drains).
// =====================================================================
__global__ __launch_bounds__(256, 2) void phase3_k(const float* __restrict__ F,
                                                   const float* ws_in,
                                                   float* __restrict__ out)
{
    __shared__ float sF[64*128];     // 32 KB
    __shared__ float so[2][4096];    // 32 KB: 2 concurrent waves' out staging
    const int tid = threadIdx.x;
    const int w = tid >> 6, l = tid & 63;
    const int blk = blockIdx.x;
    const int s0 = 16*blk + 1;
    const int nst = min(16, SEQ - s0);
    const int s0c = s0 + 4*w;
    const int nstc = min(4, SEQ - s0c);
    const int c = l & 31;
    const uintptr_t wsa = (uintptr_t)ws_in;

    // chunk entry state (down-swept), 256 B/instr coalesced reads
    const float* stt = g_cbuf + (size_t)(4*blk + w) * 2048;
    float up[16], vp[16], acc[16];
    #pragma unroll
    for (int d = 0; d < 16; ++d) { up[d] = stt[d*64 + l]; vp[d] = stt[(16+d)*64 + l]; }

    float vo[4][16], ao[4][16];
    float* so_w = &so[w & 1][0];
    float* gu = out + UOFF + (size_t)s0c * ND;
    float* gv = out + VOFF + (size_t)s0c * ND;
    float* ga = out + AOFF + (size_t)s0c * ND;

    stage_half(F, sF, l, w, s0, nst, 0);
    __syncthreads();
    if (w < 2) {
        #pragma unroll
        for (int i = 0; i < 4; ++i) {
            const int t = 4*w + i;                 // 0..7, always < nst
            newmark_step_lds(wsa, sF, l, t & 7, up, vp, acc);
            #pragma unroll
            for (int d = 0; d < 16; ++d) {
                // pre-update state: vpo = vp - E2*acc; upo = up - DT*vpo - E1*acc
                const float vpo = vp[d] - E2*acc[d];
                const float upo = up[d] - DT*vpo - E1*acc[d];
                so_w[l*64 + ((i*16+d) ^ c)] = fmaf(C3, acc[d], upo);
                vo[i][d] = fmaf(C4, acc[d], vpo);
                ao[i][d] = acc[d];
            }
        }
        drain_arr(so_w, gu, l, nstc);
        #pragma unroll
        for (int i = 0; i < 4; ++i)
            #pragma unroll
            for (int d = 0; d < 16; ++d) so_w[l*64 + ((i*16+d) ^ c)] = vo[i][d];
        drain_arr(so_w, gv, l, nstc);
        #pragma unroll
        for (int i = 0; i < 4; ++i)
            #pragma unroll
            for (int d = 0; d < 16; ++d) so_w[l*64 + ((i*16+d) ^ c)] = ao[i][d];
        drain_arr(so_w, ga, l, nstc);
    }
    __syncthreads();
    stage_half(F, sF, l, w, s0, nst, 1);
    __syncthreads();
    if (w >= 2) {
        #pragma unroll
        for (int i = 0; i < 4; ++i) {
            const int t = 4*w + i;                 // 8..15
            if (t < nst) {
                newmark_step_lds(wsa, sF, l, t & 7, up, vp, acc);
                #pragma unroll
                for (int d = 0; d < 16; ++d) {
                    const float vpo = vp[d] - E2*acc[d];
                    const float upo = up[d] - DT*vpo - E1*acc[d];
                    so_w[l*64 + ((i*16+d) ^ c)] = fmaf(C3, acc[d], upo);
                    vo[i][d] = fmaf(C4, acc[d], vpo);
                    ao[i][d] = acc[d];
                }
            }
        }
        drain_arr(so_w, gu, l, nstc);
        #pragma unroll
        for (int i = 0; i < 4; ++i)
            #pragma unroll
            for (int d = 0; d < 16; ++d) so_w[l*64 + ((i*16+d) ^ c)] = vo[i][d];
        drain_arr(so_w, gv, l, nstc);
        #pragma unroll
        for (int i = 0; i < 4; ++i)
            #pragma unroll
            for (int d = 0; d < 16; ++d) so_w[l*64 + ((i*16+d) ^ c)] = ao[i][d];
        drain_arr(so_w, ga, l, nstc);
    }
}

// =====================================================================
// Hierarchy: 2048 4-step chunks, radix-8 (R3's proven wiring):
//   up:  G4 (256 grps, on g_cbuf) -> G32 (32) -> G256 (4) ->
//        top G2048 (1 grp, 4 it, seed P1, starts into T3)
//   down: G256 -> G32 -> G4 (entry states into g_cbuf)
// Tail chunk (3 steps): its mis-sized total feeds no later prefix.
// =====================================================================
extern "C" void kernel_launch(void* const* d_in, const int* in_sizes, int n_in,
                              void* d_out, int out_size, void* d_ws, size_t ws_size,
                              hipStream_t stream)
{
    const float* F = (const float*)d_in[0];
    const float* M = (const float*)d_in[1];
    const float* C = (const float*)d_in[2];
    const float* K = (const float*)d_in[3];
    float* out = (float*)d_out;
    float* ws  = (float*)d_ws;

    setup_k <<<1,   512, 0, stream>>>(F, M, C, K, ws, out);
    phase1_k<<<512, 256, 0, stream>>>(F, ws);
    scan_k<<<256, 256, 0, stream>>>(ws + WS_G4,   nullptr,    1, nullptr,    ws + WS_T1, 8);
    scan_k<<<32,  256, 0, stream>>>(ws + WS_G32,  ws + WS_T1, 0, nullptr,    ws + WS_T2, 8);
    scan_k<<<4,   256, 0, stream>>>(ws + WS_G256, ws + WS_T2, 0, nullptr,    ws + WS_T3, 8);
    scan_k<<<1,   256, 0, stream>>>(ws + WS_G2048,ws + WS_T3, 0, ws + WS_P1, nullptr,    4);
    scan_k<<<4,   256, 0, stream>>>(ws + WS_G256, ws + WS_T2, 0, ws + WS_T3, nullptr,    8);
    scan_k<<<32,  256, 0, stream>>>(ws + WS_G32,  ws + WS_T1, 0, ws + WS_T2, nullptr,    8);
    scan_k<<<256, 256, 0, stream>>>(ws + WS_G4,   nullptr,    1, ws + WS_T1, nullptr,    8);
    phase3_k<<<512, 256, 0, stream>>>(F, ws, out);
}

// Round 7
// 306.088 us; speedup vs baseline: 4.8584x; 1.2920x over previous
//
#include <hip/hip_runtime.h>
#include <stdint.h>

// ---------------- problem constants ----------------
constexpr int   SEQ  = 8192;
constexpr int   NB   = 64;
constexpr int   ND   = 16;
constexpr float DT    = 0.01f;
constexpr float BETA  = 0.25f;
constexpr float GAMMA = 0.5f;
constexpr float C1 = (0.5f - BETA) * DT * DT;
constexpr float C2 = (1.0f - GAMMA) * DT;
constexpr float C3 = BETA * DT * DT;
constexpr float C4 = GAMMA * DT;
constexpr float E1 = C1 + C3 + DT * C4;   // up' = up + DT*vp + E1*acc
constexpr float E2 = C2 + C4;             // vp' = vp + E2*acc
constexpr float GDT  = GAMMA * DT;
constexpr float BDT2 = BETA * DT * DT;

constexpr size_t BSTRIDE = (size_t)SEQ * ND;
constexpr size_t UOFF = 0;
constexpr size_t VOFF = (size_t)NB * SEQ * ND;
constexpr size_t AOFF = 2 * VOFF;

// ws layout (float offsets), ~2.4 MB
constexpr int WS_A1T   = 0;                    // 768: A1^T,A2^T,A3^T (j*16+d)
constexpr int WS_G4    = 768;                  // 1024 each, 32x32 row-major
constexpr int WS_G32   = 1792;
constexpr int WS_G256  = 2816;
constexpr int WS_G2048 = 3840;
constexpr int WS_P1    = 4864;                 // 2048: state entering step 1, [r*64+b]
constexpr int WS_T1    = 8192;                 // 256 * 2048
constexpr int WS_T2    = WS_T1 + 256 * 2048;   // 32  * 2048
constexpr int WS_T3    = WS_T2 + 32 * 2048;    // 4   * 2048

// 2048 4-step chunk totals (up-sweep) -> chunk entry states (down-sweep).
// Layout [chunk][r*64 + b]: 256 B-contiguous per instruction (R5-proven).
__device__ float g_cbuf[(size_t)2048 * 2048];

// ---------------------------------------------------------------------
// Stage one 8-step half of a block's F tile into LDS (XOR-swizzled).
// Per instruction: 2 batches x 512 B fully contiguous (R0/R5-proven).
// sF[b*128 + (W ^ (b&31))], W = step_in_half*16 + d.
// ---------------------------------------------------------------------
__device__ __forceinline__ void stage_half(const float* __restrict__ F, float* __restrict__ sF,
                                           int l, int w, int s0, int nst, int h)
{
    const int lw  = l & 31;
    const int sin = lw >> 2;
    const bool valid = (8*h + sin) < nst;
    const int W0 = 4*lw;
    #pragma unroll
    for (int p = 0; p < 8; ++p) {
        const int b = p*8 + w*2 + (l >> 5);
        float4 x = make_float4(0.f,0.f,0.f,0.f);
        if (valid) x = *(const float4*)(F + (size_t)b * BSTRIDE + (size_t)(s0 + 8*h) * ND + W0);
        const int cb = b & 31;
        sF[b*128 + ((W0+0) ^ cb)] = x.x;
        sF[b*128 + ((W0+1) ^ cb)] = x.y;
        sF[b*128 + ((W0+2) ^ cb)] = x.z;
        sF[b*128 + ((W0+3) ^ cb)] = x.w;
    }
}

// ---------------------------------------------------------------------
// Matrix broadcast via v_readlane: the 768 constants A1^T|A2^T|A3^T live
// distributed across the wave in 12 VGPRs (mm[t][lane] = A_all[t*64+lane]).
// Each FMA's wave-uniform operand = readlane(mm[idx>>6], idx&63) -> SGPR.
// Zero memory traffic in the inner loop.
// ---------------------------------------------------------------------
__device__ __forceinline__ float rlane(uint32_t v, int lane)
{
    return __uint_as_float(__builtin_amdgcn_readlane(v, lane));
}

__device__ __forceinline__ void load_mm(const float* __restrict__ ws, int l, uint32_t (&mm)[12])
{
    #pragma unroll
    for (int t = 0; t < 12; ++t) mm[t] = __float_as_uint(ws[WS_A1T + t*64 + l]);
}

// acc = A1*f - A3*up - A2*vp   (NO state update -- callers update explicitly;
// R6's bug was this function updating AND the caller updating again)
__device__ __forceinline__ void nm_acc_rl(uint32_t (&mm)[12], const float* __restrict__ sF,
                                          int l, int sin,
                                          const float (&up)[16], const float (&vp)[16],
                                          float (&acc)[16])
{
    // anti-LICM: make mm "change" each call so the 768 readlanes cannot be
    // hoisted out of the step loop into (nonexistent) persistent SGPRs.
    asm volatile("" : "+v"(mm[0]), "+v"(mm[1]), "+v"(mm[2]),  "+v"(mm[3]),
                      "+v"(mm[4]), "+v"(mm[5]), "+v"(mm[6]),  "+v"(mm[7]),
                      "+v"(mm[8]), "+v"(mm[9]), "+v"(mm[10]), "+v"(mm[11]));
    const int c = l & 31;
    const int base = l*128;
    float f[16];
    #pragma unroll
    for (int d = 0; d < 16; ++d) f[d] = sF[base + ((sin*16 + d) ^ c)];
    #pragma unroll
    for (int d = 0; d < 16; ++d) acc[d] = 0.f;
    #pragma unroll
    for (int j = 0; j < 16; ++j) {
        const float fj = f[j], nu = -up[j], nv = -vp[j];
        #pragma unroll
        for (int d = 0; d < 16; ++d) {
            const int i1 = j*16 + d;          // A1
            const int i2 = 256 + i1;          // A2
            const int i3 = 512 + i1;          // A3
            acc[d] = fmaf(rlane(mm[i1 >> 6], i1 & 63), fj, acc[d]);
            acc[d] = fmaf(rlane(mm[i3 >> 6], i3 & 63), nu, acc[d]);
            acc[d] = fmaf(rlane(mm[i2 >> 6], i2 & 63), nv, acc[d]);
        }
    }
}

__device__ __forceinline__ void nm_update(float (&up)[16], float (&vp)[16], const float (&acc)[16])
{
    #pragma unroll
    for (int d = 0; d < 16; ++d) {
        up[d] = fmaf(DT, vp[d], up[d]);   // uses pre-update vp
        up[d] = fmaf(E1, acc[d], up[d]);
        vp[d] = fmaf(E2, acc[d], vp[d]);
    }
}

// ---------------------------------------------------------------------
// Per-step per-wave output drain: stage one 16x64 tile in the wave's own
// 4 KB LDS slice, wave-synchronous transpose, then 4 global_store_dwordx4
// covering 16 batches x 64 B contiguous per instruction.
// Quad swizzle s=(q+(b>>2))&3: bank class spans {b0,b2,b3} -> 8-way
// (the floor for a 1 KB wave access; R6's (q^b)&3 was 16-way).
// ---------------------------------------------------------------------
__device__ __forceinline__ void out_step(float* __restrict__ so_w,
                                         float* __restrict__ gdst,
                                         int l, const float (&vals)[16])
{
    const int b = l;
    #pragma unroll
    for (int q = 0; q < 4; ++q) {
        float4 x = make_float4(vals[4*q+0], vals[4*q+1], vals[4*q+2], vals[4*q+3]);
        *(float4*)(so_w + b*16 + (((q + (b >> 2)) & 3) * 4)) = x;
    }
    const int bb = l >> 2;     // batch-within-16-group
    const int q  = l & 3;      // dword-quad
    #pragma unroll
    for (int g = 0; g < 4; ++g) {
        const int batch = g*16 + bb;
        float4 x = *(const float4*)(so_w + batch*16 + (((q + (batch >> 2)) & 3) * 4));
        *(float4*)(gdst + (size_t)batch * BSTRIDE + 4*q) = x;
    }
}

// =====================================================================
// K0: invert K_eff & M, A2/A3 (transposed to ws), G powers
// {4,32,256,2048}, p1 seed, step-0 outputs. One block, 512 threads.
// (byte-identical to R5 -- proven)
// =====================================================================
__global__ __launch_bounds__(512) void setup_k(const float* __restrict__ F,
                                               const float* __restrict__ Mg,
                                               const float* __restrict__ Cg,
                                               const float* __restrict__ Kg,
                                               float* __restrict__ ws,
                                               float* __restrict__ out)
{
    __shared__ float sM[256], sC[256], sK[256];
    __shared__ float aug[16][33];
    __shared__ float A1s[256], A2s[256], A3s[256], Mis[256];
    __shared__ float bA[1024], bB[1024];
    const int tid = threadIdx.x;
    if (tid < 256) { sM[tid] = Mg[tid]; sC[tid] = Cg[tid]; sK[tid] = Kg[tid]; }
    __syncthreads();

    const int r = tid >> 5, c = tid & 31;
    {
        float v;
        if (c < 16) v = sM[r*16+c] + GDT * sC[r*16+c] + BDT2 * sK[r*16+c];
        else        v = (c - 16 == r) ? 1.f : 0.f;
        aug[r][c] = v;
    }
    __syncthreads();
    for (int kk = 0; kk < 16; ++kk) {
        float pv   = aug[kk][kk];
        float fr   = aug[r][kk];
        float akc  = aug[kk][c];
        float curv = aug[r][c];
        __syncthreads();
        float inv = 1.0f / pv;
        aug[r][c] = (r == kk) ? curv * inv : fmaf(-fr * inv, akc, curv);
        __syncthreads();
    }
    if (tid < 256) A1s[tid] = aug[tid >> 4][(tid & 15) + 16];
    __syncthreads();

    aug[r][c] = (c < 16) ? sM[r*16+c] : ((c - 16 == r) ? 1.f : 0.f);
    __syncthreads();
    for (int kk = 0; kk < 16; ++kk) {
        float pv   = aug[kk][kk];
        float fr   = aug[r][kk];
        float akc  = aug[kk][c];
        float curv = aug[r][c];
        __syncthreads();
        float inv = 1.0f / pv;
        aug[r][c] = (r == kk) ? curv * inv : fmaf(-fr * inv, akc, curv);
        __syncthreads();
    }
    if (tid < 256) Mis[tid] = aug[tid >> 4][(tid & 15) + 16];
    __syncthreads();

    if (tid < 256) {
        const int rr = tid >> 4, cc = tid & 15;
        float a2 = 0.f, a3 = 0.f;
        #pragma unroll
        for (int j = 0; j < 16; ++j) {
            const float a = A1s[rr*16+j];
            a2 = fmaf(a, sC[j*16+cc], a2);
            a3 = fmaf(a, sK[j*16+cc], a3);
        }
        A2s[tid] = a2; A3s[tid] = a3;
    }
    __syncthreads();

    if (tid < 256) {
        const int j = tid >> 4, d = tid & 15;
        ws[WS_A1T +       tid] = A1s[d*16+j];
        ws[WS_A1T + 256 + tid] = A2s[d*16+j];
        ws[WS_A1T + 512 + tid] = A3s[d*16+j];
    }
    for (int idx = tid; idx < 1024; idx += 512) {
        const int i = idx >> 5, j = idx & 31;
        float v;
        if (i < 16) {
            if (j < 16) v = ((i == j) ? 1.f : 0.f) - E1 * A3s[i*16+j];
            else        v = ((i == j - 16) ? DT : 0.f) - E1 * A2s[i*16+(j-16)];
        } else {
            const int i2 = i - 16;
            if (j < 16) v = -E2 * A3s[i2*16+j];
            else        v = ((i2 == j - 16) ? 1.f : 0.f) - E2 * A2s[i2*16+(j-16)];
        }
        bA[idx] = v;
    }
    __syncthreads();
    // after iter s: bA = G^(2^(s+1)); store G4(s=1), G32(s=4), G256(s=7), G2048(end)
    for (int s = 0; s < 11; ++s) {
        for (int idx = tid; idx < 1024; idx += 512) {
            const int i = idx >> 5, j = idx & 31;
            float acc = 0.f;
            #pragma unroll
            for (int q = 0; q < 32; ++q) acc = fmaf(bA[i*32+q], bA[q*32+j], acc);
            bB[idx] = acc;
        }
        __syncthreads();
        for (int idx = tid; idx < 1024; idx += 512) bA[idx] = bB[idx];
        __syncthreads();
        if (s == 1) for (int idx = tid; idx < 1024; idx += 512) ws[WS_G4   + idx] = bA[idx];
        if (s == 4) for (int idx = tid; idx < 1024; idx += 512) ws[WS_G32  + idx] = bA[idx];
        if (s == 7) for (int idx = tid; idx < 1024; idx += 512) ws[WS_G256 + idx] = bA[idx];
    }
    for (int idx = tid; idx < 1024; idx += 512) ws[WS_G2048 + idx] = bA[idx];

    // step-0 outputs + p1 seed (state entering step 1): up=C1*a0, vp=C2*a0
    for (int t = tid; t < 1024; t += 512) {
        const int b = t >> 4, d = t & 15;
        float s0 = 0.f;
        #pragma unroll
        for (int j = 0; j < 16; ++j) s0 = fmaf(Mis[d*16+j], F[(size_t)b * BSTRIDE + j], s0);
        out[UOFF + (size_t)b * BSTRIDE + d] = 0.f;
        out[VOFF + (size_t)b * BSTRIDE + d] = 0.f;
        out[AOFF + (size_t)b * BSTRIDE + d] = s0;
        ws[WS_P1 + d*64 + b]        = C1 * s0;
        ws[WS_P1 + (16 + d)*64 + b] = C2 * s0;
    }
}

// =====================================================================
// K1: 4-step chunk totals. 512 blocks x 256 thr; both halves staged
// up-front (one barrier); wave w = chunk 4*blk+w, exactly 4 steps from
// zero via readlane-matrix core. Totals -> g_cbuf [r*64+b].
// =====================================================================
__global__ __launch_bounds__(256, 2) void phase1_k(const float* __restrict__ F,
                                                   const float* __restrict__ ws)
{
    __shared__ float sF0[64*128];   // 32 KB: steps 0-7
    __shared__ float sF1[64*128];   // 32 KB: steps 8-15
    const int tid = threadIdx.x;
    const int w = tid >> 6, l = tid & 63;
    const int blk = blockIdx.x;
    const int s0 = 16*blk + 1;
    const int nst = min(16, SEQ - s0);

    uint32_t mm[12];
    load_mm(ws, l, mm);

    float up[16], vp[16], acc[16];
    #pragma unroll
    for (int d = 0; d < 16; ++d) { up[d] = 0.f; vp[d] = 0.f; }

    stage_half(F, sF0, l, w, s0, nst, 0);
    stage_half(F, sF1, l, w, s0, nst, 1);
    __syncthreads();

    const float* sFw = (w < 2) ? sF0 : sF1;
    #pragma unroll 1
    for (int i = 0; i < 4; ++i) {
        const int t = 4*w + i;
        if (t < nst) {
            nm_acc_rl(mm, sFw, l, t & 7, up, vp, acc);
            nm_update(up, vp, acc);
        }
    }

    float* cb = g_cbuf + (size_t)(4*blk + w) * 2048;
    #pragma unroll
    for (int d = 0; d < 16; ++d) { cb[d*64 + l] = up[d]; cb[(16+d)*64 + l] = vp[d]; }
}

// =====================================================================
// K2: affine scan p' = Gm*p + c_k (byte-identical to R5 -- proven).
// =====================================================================
__global__ __launch_bounds__(256, 4) void scan_k(const float* __restrict__ Gm,
                                                 float* cbase_ws, int use_gcbuf,
                                                 const float* __restrict__ seed,
                                                 float* __restrict__ totals,
                                                 int nIter)
{
    alignas(16) __shared__ float sG[1024];
    __shared__ float pb[2][2048];
    float* cbase = use_gcbuf ? g_cbuf : cbase_ws;
    const int tid = threadIdx.x;
    const int b = tid & 63;
    const int w = tid >> 6;
    const int g = blockIdx.x;
    for (int i = tid; i < 1024; i += 256) sG[i] = Gm[i];

    float pr[8];
    #pragma unroll
    for (int q = 0; q < 8; ++q) {
        const int r = w + 4*q;
        pr[q] = (seed != nullptr) ? seed[(size_t)g * 2048 + r*64 + b] : 0.f;
        pb[0][r*64 + b] = pr[q];
    }
    __syncthreads();
    int cur = 0;
    float* cslot = cbase + (size_t)g * nIter * 2048;
    for (int k = 0; k < nIter; ++k) {
        float n[8];
        #pragma unroll
        for (int q = 0; q < 8; ++q) n[q] = cslot[(w + 4*q)*64 + b];       // c_k (old)
        if (totals == nullptr) {
            #pragma unroll
            for (int q = 0; q < 8; ++q) cslot[(w + 4*q)*64 + b] = pr[q];  // write start
        }
        #pragma unroll
        for (int j4 = 0; j4 < 8; ++j4) {
            const float p0 = pb[cur][(4*j4+0)*64 + b];
            const float p1 = pb[cur][(4*j4+1)*64 + b];
            const float p2 = pb[cur][(4*j4+2)*64 + b];
            const float p3 = pb[cur][(4*j4+3)*64 + b];
            #pragma unroll
            for (int q = 0; q < 8; ++q) {
                const float4 gq = *(const float4*)&sG[(w + 4*q)*32 + 4*j4];
                n[q] = fmaf(gq.x, p0, n[q]);
                n[q] = fmaf(gq.y, p1, n[q]);
                n[q] = fmaf(gq.z, p2, n[q]);
                n[q] = fmaf(gq.w, p3, n[q]);
            }
        }
        #pragma unroll
        for (int q = 0; q < 8; ++q) { pr[q] = n[q]; pb[cur ^ 1][(w + 4*q)*64 + b] = n[q]; }
        cur ^= 1;
        cslot += 2048;
        __syncthreads();
    }
    if (totals != nullptr) {
        #pragma unroll
        for (int q = 0; q < 8; ++q) totals[(size_t)g * 2048 + (w + 4*q)*64 + b] = pr[q];
    }
}

// =====================================================================
// K3: outputs. 512 blocks x 256 thr; wave w = chunk 4*blk+w from its
// down-swept entry state; exactly 4 steps/wave. readlane-matrix core;
// outputs computed from PRE-update predictors (u_n = up + C3*acc,
// v_n = vp + C4*acc, a_n = acc), then ONE update (R6 double-updated).
// Per-step per-wave drains through a private 4 KB so slice.
// LDS = 64 KB (sF both halves) + 16 KB (so) = 80 KB -> 2 blocks/CU.
// =====================================================================
__global__ __launch_bounds__(256, 2) void phase3_k(const float* __restrict__ F,
                                                   const float* __restrict__ ws,
                                                   float* __restrict__ out)
{
    __shared__ float sF0[64*128];            // 32 KB: steps 0-7
    __shared__ float sF1[64*128];            // 32 KB: steps 8-15
    alignas(16) __shared__ float so[4][1024];// 16 KB: per-wave drain slices
    const int tid = threadIdx.x;
    const int w = tid >> 6, l = tid & 63;
    const int blk = blockIdx.x;
    const int s0 = 16*blk + 1;
    const int nst = min(16, SEQ - s0);
    const int s0c = s0 + 4*w;

    uint32_t mm[12];
    load_mm(ws, l, mm);

    // chunk entry state (down-swept), 256 B/instr coalesced reads
    const float* stt = g_cbuf + (size_t)(4*blk + w) * 2048;
    float up[16], vp[16], acc[16];
    #pragma unroll
    for (int d = 0; d < 16; ++d) { up[d] = stt[d*64 + l]; vp[d] = stt[(16+d)*64 + l]; }

    stage_half(F, sF0, l, w, s0, nst, 0);
    stage_half(F, sF1, l, w, s0, nst, 1);
    __syncthreads();

    const float* sFw = (w < 2) ? sF0 : sF1;
    float* so_w = &so[w][0];
    float* gu = out + UOFF + (size_t)s0c * ND;
    float* gv = out + VOFF + (size_t)s0c * ND;
    float* ga = out + AOFF + (size_t)s0c * ND;

    #pragma unroll 1
    for (int i = 0; i < 4; ++i) {
        const int t = 4*w + i;
        if (t < nst) {
            nm_acc_rl(mm, sFw, l, t & 7, up, vp, acc);
            float o[16];
            #pragma unroll
            for (int d = 0; d < 16; ++d) o[d] = fmaf(C3, acc[d], up[d]);   // u_n (pre-update up)
            out_step(so_w, gu + i*ND, l, o);
            #pragma unroll
            for (int d = 0; d < 16; ++d) o[d] = fmaf(C4, acc[d], vp[d]);   // v_n (pre-update vp)
            out_step(so_w, gv + i*ND, l, o);
            out_step(so_w, ga + i*ND, l, acc);                             // a_n
            nm_update(up, vp, acc);                                        // ONE update
        }
    }
}

// =====================================================================
// Hierarchy (R5-proven wiring): 2048 4-step chunks, radix-8:
//   up:  G4 (256 grps, on g_cbuf) -> G32 (32) -> G256 (4) ->
//        top G2048 (1 grp, 4 it, seed P1, starts into T3)
//   down: G256 -> G32 -> G4 (entry states into g_cbuf)
// =====================================================================
extern "C" void kernel_launch(void* const* d_in, const int* in_sizes, int n_in,
                              void* d_out, int out_size, void* d_ws, size_t ws_size,
                              hipStream_t stream)
{
    const float* F = (const float*)d_in[0];
    const float* M = (const float*)d_in[1];
    const float* C = (const float*)d_in[2];
    const float* K = (const float*)d_in[3];
    float* out = (float*)d_out;
    float* ws  = (float*)d_ws;

    setup_k <<<1,   512, 0, stream>>>(F, M, C, K, ws, out);
    phase1_k<<<512, 256, 0, stream>>>(F, ws);
    scan_k<<<256, 256, 0, stream>>>(ws + WS_G4,   nullptr,    1, nullptr,    ws + WS_T1, 8);
    scan_k<<<32,  256, 0, stream>>>(ws + WS_G32,  ws + WS_T1, 0, nullptr,    ws + WS_T2, 8);
    scan_k<<<4,   256, 0, stream>>>(ws + WS_G256, ws + WS_T2, 0, nullptr,    ws + WS_T3, 8);
    scan_k<<<1,   256, 0, stream>>>(ws + WS_G2048,ws + WS_T3, 0, ws + WS_P1, nullptr,    4);
    scan_k<<<4,   256, 0, stream>>>(ws + WS_G256, ws + WS_T2, 0, ws + WS_T3, nullptr,    8);
    scan_k<<<32,  256, 0, stream>>>(ws + WS_G32,  ws + WS_T1, 0, ws + WS_T2, nullptr,    8);
    scan_k<<<256, 256, 0, stream>>>(ws + WS_G4,   nullptr,    1, ws + WS_T1, nullptr,    8);
    phase3_k<<<512, 256, 0, stream>>>(F, ws, out);
}